// Round 6
// baseline (723.509 us; speedup 1.0000x reference)
//
#include <hip/hip_runtime.h>
#include <hip/hip_bf16.h>
#include <stdint.h>

// QuantLinear GPTQ 4-bit: out[8192,11008] = x[8192,4096] . W[4096,11008] + bias
#define M_DIM 8192
#define K_DIM 4096
#define N_DIM 11008

typedef __bf16 bf16x8 __attribute__((ext_vector_type(8)));
typedef float f32x4 __attribute__((ext_vector_type(4)));

typedef __attribute__((address_space(1))) const void global_cvoid;
typedef __attribute__((address_space(3))) void lds_void;

__device__ __forceinline__ unsigned short f2bf(float f) {
  unsigned int u = __float_as_uint(f);
  u += 0x7fffu + ((u >> 16) & 1u);
  return (unsigned short)(u >> 16);
}

__device__ __forceinline__ void gload_lds16(const void* g, void* l) {
  // async global->LDS: each lane's 16B lands at lds_base + lane*16 (linear dest)
  __builtin_amdgcn_global_load_lds((global_cvoid*)g, (lds_void*)l, 16, 0, 0);
}

// ---------------- stage 1: x fp32 -> bf16 ----------------
__global__ void k_convert_x(const float* __restrict__ x, unsigned short* __restrict__ xb) {
  const int nthreads = gridDim.x * blockDim.x;
  int tid = blockIdx.x * blockDim.x + threadIdx.x;
  const int n8 = (M_DIM * K_DIM) / 8;
  for (int i = tid; i < n8; i += nthreads) {
    const float4* p = (const float4*)x + (size_t)i * 2;
    float4 a = p[0], b = p[1];
    union { unsigned short h[8]; uint4 u; } r;
    r.h[0] = f2bf(a.x); r.h[1] = f2bf(a.y); r.h[2] = f2bf(a.z); r.h[3] = f2bf(a.w);
    r.h[4] = f2bf(b.x); r.h[5] = f2bf(b.y); r.h[6] = f2bf(b.z); r.h[7] = f2bf(b.w);
    ((uint4*)xb)[i] = r.u;
  }
}

// ---------------- stage 2: dequant W -> bf16 W^T [N][K] ----------------
__global__ void k_dequant_w(const int* __restrict__ qw, const int* __restrict__ qz,
                            const float* __restrict__ sc, unsigned short* __restrict__ wt) {
  int n = blockIdx.x * blockDim.x + threadIdx.x;
  int k8_0 = blockIdx.y * 8;
  int g = (k8_0 * 8) >> 7;
  float s = sc[g * N_DIM + n];
  int zq = (qz[g * (N_DIM / 8) + (n >> 3)] >> ((n & 7) * 4)) & 15;
  float zs = s * (float)zq;
  #pragma unroll
  for (int i = 0; i < 8; ++i) {
    int k8 = k8_0 + i;
    int w = qw[(size_t)k8 * N_DIM + n];
    union { unsigned short h[8]; uint4 u; } r;
    #pragma unroll
    for (int j = 0; j < 8; ++j) {
      float v = s * (float)((w >> (4 * j)) & 15) - zs;
      r.h[j] = f2bf(v);
    }
    *(uint4*)(wt + (size_t)n * K_DIM + (size_t)k8 * 8) = r.u;
  }
}

// ---------------- stage 3: 256x256 8-phase bf16 GEMM (staggered lgkm) ----------------
// A = Xb [M][K], B = Wt [N][K]. 8 waves (2Mx4N), BK=64, dbuf swizzled LDS.
// Phase = {stage-issue; ds-reads; MFMA (compiler-staggered lgkm waits); [vmcnt]; barrier}.
// No explicit lgkmcnt(0): every ds_read is consumed by a same-phase MFMA, so the
// waitcnt pass drains each read before its consumer issues -> all reads complete
// before the phase-end barrier -> the round-5 stage/read separation invariant
// holds (stage of a region is >=1 barrier after its last reader's drain).
// Compile-order pinned by "memory" asm around each barrier.
// Swizzle: 16B slot ^= (row&7) on stage-source and reads (involution).

#define MFMA1(mi, nj, kk) \
  acc[mi][nj] = __builtin_amdgcn_mfma_f32_16x16x32_bf16(afr[(mi) & 1][kk], bfr[nj][kk], acc[mi][nj], 0, 0, 0)

#define MFMAQ(q) do { \
  __builtin_amdgcn_s_setprio(1); \
  MFMA1((q)*2+0, 0, 0); MFMA1((q)*2+0, 1, 0); MFMA1((q)*2+0, 2, 0); MFMA1((q)*2+0, 3, 0); \
  MFMA1((q)*2+1, 0, 0); MFMA1((q)*2+1, 1, 0); MFMA1((q)*2+1, 2, 0); MFMA1((q)*2+1, 3, 0); \
  MFMA1((q)*2+0, 0, 1); MFMA1((q)*2+0, 1, 1); MFMA1((q)*2+0, 2, 1); MFMA1((q)*2+0, 3, 1); \
  MFMA1((q)*2+1, 0, 1); MFMA1((q)*2+1, 1, 1); MFMA1((q)*2+1, 2, 1); MFMA1((q)*2+1, 3, 1); \
  __builtin_amdgcn_s_setprio(0); \
} while (0)

#define LOADA(buf, q) do { \
  const unsigned short* aa_ = sh + (((buf)*2)*2 + wm) * 8192 + (q) * 2048; \
  afr[0][0] = *(const bf16x8*)(const void*)(aa_ + aoff0); \
  afr[0][1] = *(const bf16x8*)(const void*)(aa_ + aoff1); \
  afr[1][0] = *(const bf16x8*)(const void*)(aa_ + 1024 + aoff0); \
  afr[1][1] = *(const bf16x8*)(const void*)(aa_ + 1024 + aoff1); \
} while (0)

#define LOADB(buf) do { \
  const unsigned short* bb_ = sh + (((buf)*2 + 1)*2 + (wn >> 1)) * 8192; \
  bfr[0][0] = *(const bf16x8*)(const void*)(bb_ + boff0); \
  bfr[0][1] = *(const bf16x8*)(const void*)(bb_ + boff1); \
  bfr[1][0] = *(const bf16x8*)(const void*)(bb_ + 1024 + boff0); \
  bfr[1][1] = *(const bf16x8*)(const void*)(bb_ + 1024 + boff1); \
  bfr[2][0] = *(const bf16x8*)(const void*)(bb_ + 2048 + boff0); \
  bfr[2][1] = *(const bf16x8*)(const void*)(bb_ + 2048 + boff1); \
  bfr[3][0] = *(const bf16x8*)(const void*)(bb_ + 3072 + boff0); \
  bfr[3][1] = *(const bf16x8*)(const void*)(bb_ + 3072 + boff1); \
} while (0)

#define STAGE(buf, ab, half, kt) do { \
  const unsigned short* g_ = ((ab) ? pB : pA) + ((size_t)(half) * 128) * K_DIM + (kt) * 64; \
  unsigned short* l_ = sh + ((((buf)*2 + (ab))*2 + (half)) * 8192) + w * 1024; \
  gload_lds16(g_, l_); \
  gload_lds16(g_ + 8 * K_DIM, l_ + 512); \
} while (0)

#define NOSTMT ((void)0)
#define WAIT_VM4 asm volatile("s_waitcnt vmcnt(4)" ::: "memory")
#define WAIT_VM0 asm volatile("s_waitcnt vmcnt(0)" ::: "memory")

// phase: stage issue -> ds-reads -> MFMA (auto-staggered waits) -> [vmcnt] -> barrier
#define PHASE(buf, q, DOB, S1, VW) do { \
  S1; \
  LOADA(buf, q); \
  if (DOB) LOADB(buf); \
  MFMAQ(q); \
  VW; \
  __builtin_amdgcn_s_barrier(); \
  asm volatile("" ::: "memory"); \
} while (0)

__global__ __launch_bounds__(512, 2) void k_gemm(const unsigned short* __restrict__ Xb,
                                                 const unsigned short* __restrict__ Wt,
                                                 const float* __restrict__ bias,
                                                 float* __restrict__ out) {
  __shared__ __align__(16) unsigned short sh[2 * 2 * 2 * 8192];  // 128 KiB

  const int nwg = gridDim.x;                 // 1376, % 8 == 0 -> bijective
  int bid = blockIdx.x;
  int swz = (bid & 7) * (nwg >> 3) + (bid >> 3);
  const int ntn = N_DIM / 256;               // 43
  int mt = swz / ntn;
  int nt = swz % ntn;

  const int tid = threadIdx.x;
  const int w = tid >> 6;        // wave 0..7
  const int lane = tid & 63;
  const int wm = w >> 2;         // 0..1 (M sub-tile 128)
  const int wn = w & 3;          // 0..3 (N sub-tile 64)
  const int fr = lane & 15;
  const int fq = lane >> 4;

  // staging: per-lane pre-swizzled global source (involution slot^row)
  const int srow = lane >> 3;                 // 0..7
  const int sslot = (lane & 7) ^ srow;        // 16B slot in the 128B row
  const size_t goff = (size_t)srow * K_DIM + (size_t)sslot * 8;
  const unsigned short* pA = Xb + (size_t)(mt * 256 + w * 16) * K_DIM + goff;
  const unsigned short* pB = Wt + (size_t)(nt * 256 + w * 16) * K_DIM + goff;

  // ds_read element offsets (swizzled slot = (kk*4+fq) ^ (row&7), row&7 == fr&7)
  const int aoff0 = fr * 64 + ((fq) ^ (fr & 7)) * 8;
  const int aoff1 = fr * 64 + ((4 + fq) ^ (fr & 7)) * 8;
  const int boff0 = ((wn & 1) * 64 + fr) * 64 + ((fq) ^ (fr & 7)) * 8;
  const int boff1 = ((wn & 1) * 64 + fr) * 64 + ((4 + fq) ^ (fr & 7)) * 8;

  f32x4 acc[8][4] = {};
  bf16x8 afr[2][2];
  bf16x8 bfr[4][2];

  // prologue: tile0 fully (buf0), tile1 B-halves (buf1)
  STAGE(0, 0, 0, 0); STAGE(0, 0, 1, 0); STAGE(0, 1, 0, 0); STAGE(0, 1, 1, 0);
  STAGE(1, 1, 0, 1); STAGE(1, 1, 1, 1);
  WAIT_VM4;                       // tile0's 8 loads done; B(1) x4 in flight
  __builtin_amdgcn_s_barrier();
  asm volatile("" ::: "memory");

  // main loop: iteration computes tiles 2i (buf0, P1-4) and 2i+1 (buf1, P5-8)
  for (int i = 0; i < 31; ++i) {
    int t = 2 * i;
    PHASE(0, 0, true,  STAGE(1, 0, 0, t + 1), NOSTMT);   // P1
    PHASE(0, 1, false, STAGE(1, 0, 1, t + 1), NOSTMT);   // P2
    PHASE(0, 2, false, STAGE(0, 1, 0, t + 2), NOSTMT);   // P3
    PHASE(0, 3, false, STAGE(0, 1, 1, t + 2), WAIT_VM4); // P4: tile 2i+1 ready
    PHASE(1, 0, true,  STAGE(0, 0, 0, t + 2), NOSTMT);   // P5
    PHASE(1, 1, false, STAGE(0, 0, 1, t + 2), NOSTMT);   // P6
    PHASE(1, 2, false, STAGE(1, 1, 0, t + 3), NOSTMT);   // P7
    PHASE(1, 3, false, STAGE(1, 1, 1, t + 3), WAIT_VM4); // P8: tile 2i+2 ready
  }
  // final iteration: tiles 62 (buf0), 63 (buf1); drain
  PHASE(0, 0, true,  STAGE(1, 0, 0, 63), NOSTMT);
  PHASE(0, 1, false, STAGE(1, 0, 1, 63), NOSTMT);
  PHASE(0, 2, false, NOSTMT, NOSTMT);
  PHASE(0, 3, false, NOSTMT, WAIT_VM0);
  PHASE(1, 0, true,  NOSTMT, NOSTMT);
  PHASE(1, 1, false, NOSTMT, NOSTMT);
  PHASE(1, 2, false, NOSTMT, NOSTMT);
  PHASE(1, 3, false, NOSTMT, NOSTMT);

  // epilogue: C/D layout col=lane&15, row=(lane>>4)*4+reg
  const int r0 = mt * 256 + wm * 128 + fq * 4;
  const int c0 = nt * 256 + wn * 64 + fr;
  #pragma unroll
  for (int nj = 0; nj < 4; ++nj) {
    int col = c0 + nj * 16;
    float bv = bias[col];
    #pragma unroll
    for (int mi = 0; mi < 8; ++mi) {
      size_t base = (size_t)(r0 + mi * 16) * N_DIM + col;
      #pragma unroll
      for (int r = 0; r < 4; ++r)
        out[base + (size_t)r * N_DIM] = acc[mi][nj][r] + bv;
    }
  }
}

// ---------------- fallback (ws too small): naive fp32 ----------------
__global__ void k_fallback(const float* __restrict__ x, const int* __restrict__ qw,
                           const int* __restrict__ qz, const float* __restrict__ sc,
                           const float* __restrict__ bias, float* __restrict__ out) {
  int n = blockIdx.x * blockDim.x + threadIdx.x;
  int m = blockIdx.y;
  const float* xr = x + (size_t)m * K_DIM;
  float acc = 0.f;
  for (int g = 0; g < 32; ++g) {
    float s = sc[g * N_DIM + n];
    int zq = (qz[g * (N_DIM / 8) + (n >> 3)] >> ((n & 7) * 4)) & 15;
    float zs = s * (float)zq;
    for (int k8 = g * 16; k8 < g * 16 + 16; ++k8) {
      int w = qw[(size_t)k8 * N_DIM + n];
      #pragma unroll
      for (int j = 0; j < 8; ++j) {
        float wf = s * (float)((w >> (4 * j)) & 15) - zs;
        acc += wf * xr[k8 * 8 + j];
      }
    }
  }
  out[(size_t)m * N_DIM + n] = acc + bias[n];
}

extern "C" void kernel_launch(void* const* d_in, const int* in_sizes, int n_in,
                              void* d_out, int out_size, void* d_ws, size_t ws_size,
                              hipStream_t stream) {
  const float* x  = (const float*)d_in[0];
  const int* qw   = (const int*)d_in[1];
  const int* qz   = (const int*)d_in[2];
  const float* sc = (const float*)d_in[3];
  const float* bias = (const float*)d_in[4];
  float* out = (float*)d_out;

  const size_t xb_bytes = (size_t)M_DIM * K_DIM * 2;
  const size_t wt_bytes = (size_t)N_DIM * K_DIM * 2;
  const size_t need = xb_bytes + wt_bytes;

  if (ws_size >= need) {
    unsigned short* xb = (unsigned short*)d_ws;
    unsigned short* wt = (unsigned short*)((char*)d_ws + xb_bytes);
    k_convert_x<<<dim3(4096), dim3(256), 0, stream>>>(x, xb);
    k_dequant_w<<<dim3(N_DIM / 256, 64), dim3(256), 0, stream>>>(qw, qz, sc, wt);
    k_gemm<<<dim3((M_DIM / 256) * (N_DIM / 256)), dim3(512), 0, stream>>>(xb, wt, bias, out);
  } else {
    k_fallback<<<dim3(N_DIM / 256, M_DIM), dim3(256), 0, stream>>>(x, qw, qz, sc, bias, out);
  }
}

// Round 7
// 720.025 us; speedup vs baseline: 1.0048x; 1.0048x over previous
//
#include <hip/hip_runtime.h>
#include <hip/hip_bf16.h>
#include <stdint.h>

// QuantLinear GPTQ 4-bit: out[8192,11008] = x[8192,4096] . W[4096,11008] + bias
#define M_DIM 8192
#define K_DIM 4096
#define N_DIM 11008

typedef __bf16 bf16x8 __attribute__((ext_vector_type(8)));
typedef float f32x4 __attribute__((ext_vector_type(4)));

typedef __attribute__((address_space(1))) const void global_cvoid;
typedef __attribute__((address_space(3))) void lds_void;

__device__ __forceinline__ unsigned short f2bf(float f) {
  unsigned int u = __float_as_uint(f);
  u += 0x7fffu + ((u >> 16) & 1u);
  return (unsigned short)(u >> 16);
}

__device__ __forceinline__ void gload_lds16(const void* g, void* l) {
  // async global->LDS: each lane's 16B lands at lds_base + lane*16 (linear dest)
  __builtin_amdgcn_global_load_lds((global_cvoid*)g, (lds_void*)l, 16, 0, 0);
}

// ---------------- stage 1: x fp32 -> bf16 ----------------
__global__ void k_convert_x(const float* __restrict__ x, unsigned short* __restrict__ xb) {
  const int nthreads = gridDim.x * blockDim.x;
  int tid = blockIdx.x * blockDim.x + threadIdx.x;
  const int n8 = (M_DIM * K_DIM) / 8;
  for (int i = tid; i < n8; i += nthreads) {
    const float4* p = (const float4*)x + (size_t)i * 2;
    float4 a = p[0], b = p[1];
    union { unsigned short h[8]; uint4 u; } r;
    r.h[0] = f2bf(a.x); r.h[1] = f2bf(a.y); r.h[2] = f2bf(a.z); r.h[3] = f2bf(a.w);
    r.h[4] = f2bf(b.x); r.h[5] = f2bf(b.y); r.h[6] = f2bf(b.z); r.h[7] = f2bf(b.w);
    ((uint4*)xb)[i] = r.u;
  }
}

// ---------------- stage 2: dequant W -> bf16 W^T [N][K] ----------------
__global__ void k_dequant_w(const int* __restrict__ qw, const int* __restrict__ qz,
                            const float* __restrict__ sc, unsigned short* __restrict__ wt) {
  int n = blockIdx.x * blockDim.x + threadIdx.x;
  int k8_0 = blockIdx.y * 8;
  int g = (k8_0 * 8) >> 7;
  float s = sc[g * N_DIM + n];
  int zq = (qz[g * (N_DIM / 8) + (n >> 3)] >> ((n & 7) * 4)) & 15;
  float zs = s * (float)zq;
  #pragma unroll
  for (int i = 0; i < 8; ++i) {
    int k8 = k8_0 + i;
    int w = qw[(size_t)k8 * N_DIM + n];
    union { unsigned short h[8]; uint4 u; } r;
    #pragma unroll
    for (int j = 0; j < 8; ++j) {
      float v = s * (float)((w >> (4 * j)) & 15) - zs;
      r.h[j] = f2bf(v);
    }
    *(uint4*)(wt + (size_t)n * K_DIM + (size_t)k8 * 8) = r.u;
  }
}

// ---------------- stage 3: 256x256 8-phase bf16 GEMM (half-barrier) ----------------
// A = Xb [M][K], B = Wt [N][K]. 8 waves (2Mx4N), BK=64, dbuf swizzled LDS.
// Barriers only at P2/P4/P6/P8-end. Race audit (stage vs last reader):
//   buf0-B read P1, staged P3  -> P2end barrier between   OK
//   buf0-A read P1-P4, staged P5 -> P4end                  OK
//   buf1-B read P5, staged P7  -> P6end                    OK
//   buf1-A read P8, staged next-P1 -> P8end                OK
// Within each barrier-free 2-phase window, waves drift and ds_reads of the
// second phase overlap MFMAs of the first -> LDS and MFMA pipes run
// concurrently instead of serially (round-6 model: 4814 = 2483 + 2304 cyc).
// vmcnt ledger unchanged: 12 in flight at P4/P8, vmcnt(4) drains oldest 8.
// Swizzle: 16B slot ^= (row&7) on stage-source and reads (involution).

#define MFMA1(mi, nj, kk) \
  acc[mi][nj] = __builtin_amdgcn_mfma_f32_16x16x32_bf16(afr[(mi) & 1][kk], bfr[nj][kk], acc[mi][nj], 0, 0, 0)

#define MFMAQ(q) do { \
  __builtin_amdgcn_s_setprio(1); \
  MFMA1((q)*2+0, 0, 0); MFMA1((q)*2+0, 1, 0); MFMA1((q)*2+0, 2, 0); MFMA1((q)*2+0, 3, 0); \
  MFMA1((q)*2+1, 0, 0); MFMA1((q)*2+1, 1, 0); MFMA1((q)*2+1, 2, 0); MFMA1((q)*2+1, 3, 0); \
  MFMA1((q)*2+0, 0, 1); MFMA1((q)*2+0, 1, 1); MFMA1((q)*2+0, 2, 1); MFMA1((q)*2+0, 3, 1); \
  MFMA1((q)*2+1, 0, 1); MFMA1((q)*2+1, 1, 1); MFMA1((q)*2+1, 2, 1); MFMA1((q)*2+1, 3, 1); \
  __builtin_amdgcn_s_setprio(0); \
} while (0)

#define LOADA(buf, q) do { \
  const unsigned short* aa_ = sh + (((buf)*2)*2 + wm) * 8192 + (q) * 2048; \
  afr[0][0] = *(const bf16x8*)(const void*)(aa_ + aoff0); \
  afr[0][1] = *(const bf16x8*)(const void*)(aa_ + aoff1); \
  afr[1][0] = *(const bf16x8*)(const void*)(aa_ + 1024 + aoff0); \
  afr[1][1] = *(const bf16x8*)(const void*)(aa_ + 1024 + aoff1); \
} while (0)

#define LOADB(buf) do { \
  const unsigned short* bb_ = sh + (((buf)*2 + 1)*2 + (wn >> 1)) * 8192; \
  bfr[0][0] = *(const bf16x8*)(const void*)(bb_ + boff0); \
  bfr[0][1] = *(const bf16x8*)(const void*)(bb_ + boff1); \
  bfr[1][0] = *(const bf16x8*)(const void*)(bb_ + 1024 + boff0); \
  bfr[1][1] = *(const bf16x8*)(const void*)(bb_ + 1024 + boff1); \
  bfr[2][0] = *(const bf16x8*)(const void*)(bb_ + 2048 + boff0); \
  bfr[2][1] = *(const bf16x8*)(const void*)(bb_ + 2048 + boff1); \
  bfr[3][0] = *(const bf16x8*)(const void*)(bb_ + 3072 + boff0); \
  bfr[3][1] = *(const bf16x8*)(const void*)(bb_ + 3072 + boff1); \
} while (0)

#define STAGE(buf, ab, half, kt) do { \
  const unsigned short* g_ = ((ab) ? pB : pA) + ((size_t)(half) * 128) * K_DIM + (kt) * 64; \
  unsigned short* l_ = sh + ((((buf)*2 + (ab))*2 + (half)) * 8192) + w * 1024; \
  gload_lds16(g_, l_); \
  gload_lds16(g_ + 8 * K_DIM, l_ + 512); \
} while (0)

#define NOSTMT ((void)0)
#define WAIT_VM4 asm volatile("s_waitcnt vmcnt(4)" ::: "memory")
#define WAIT_VM0 asm volatile("s_waitcnt vmcnt(0)" ::: "memory")

// no-barrier phase: stage issue -> reads -> MFMA (dataflow waits)
#define PHASE_NB(buf, q, DOB, S1, VW) do { \
  S1; \
  LOADA(buf, q); \
  if (DOB) LOADB(buf); \
  MFMAQ(q); \
  VW; \
} while (0)

// barrier phase: same + end-of-window barrier
#define PHASE_B(buf, q, DOB, S1, VW) do { \
  PHASE_NB(buf, q, DOB, S1, VW); \
  __builtin_amdgcn_s_barrier(); \
  asm volatile("" ::: "memory"); \
} while (0)

__global__ __launch_bounds__(512, 2) void k_gemm(const unsigned short* __restrict__ Xb,
                                                 const unsigned short* __restrict__ Wt,
                                                 const float* __restrict__ bias,
                                                 float* __restrict__ out) {
  __shared__ __align__(16) unsigned short sh[2 * 2 * 2 * 8192];  // 128 KiB

  const int nwg = gridDim.x;                 // 1376, % 8 == 0 -> bijective
  int bid = blockIdx.x;
  int swz = (bid & 7) * (nwg >> 3) + (bid >> 3);
  const int ntn = N_DIM / 256;               // 43
  int mt = swz / ntn;
  int nt = swz % ntn;

  const int tid = threadIdx.x;
  const int w = tid >> 6;        // wave 0..7
  const int lane = tid & 63;
  const int wm = w >> 2;         // 0..1 (M sub-tile 128)
  const int wn = w & 3;          // 0..3 (N sub-tile 64)
  const int fr = lane & 15;
  const int fq = lane >> 4;

  // staging: per-lane pre-swizzled global source (involution slot^row)
  const int srow = lane >> 3;                 // 0..7
  const int sslot = (lane & 7) ^ srow;        // 16B slot in the 128B row
  const size_t goff = (size_t)srow * K_DIM + (size_t)sslot * 8;
  const unsigned short* pA = Xb + (size_t)(mt * 256 + w * 16) * K_DIM + goff;
  const unsigned short* pB = Wt + (size_t)(nt * 256 + w * 16) * K_DIM + goff;

  // ds_read element offsets (swizzled slot = (kk*4+fq) ^ (row&7), row&7 == fr&7)
  const int aoff0 = fr * 64 + ((fq) ^ (fr & 7)) * 8;
  const int aoff1 = fr * 64 + ((4 + fq) ^ (fr & 7)) * 8;
  const int boff0 = ((wn & 1) * 64 + fr) * 64 + ((fq) ^ (fr & 7)) * 8;
  const int boff1 = ((wn & 1) * 64 + fr) * 64 + ((4 + fq) ^ (fr & 7)) * 8;

  f32x4 acc[8][4] = {};
  bf16x8 afr[2][2];
  bf16x8 bfr[4][2];

  // prologue: tile0 fully (buf0), tile1 B-halves (buf1)
  STAGE(0, 0, 0, 0); STAGE(0, 0, 1, 0); STAGE(0, 1, 0, 0); STAGE(0, 1, 1, 0);
  STAGE(1, 1, 0, 1); STAGE(1, 1, 1, 1);
  WAIT_VM4;                       // tile0's 8 loads done; B(1) x4 in flight
  __builtin_amdgcn_s_barrier();
  asm volatile("" ::: "memory");

  // main loop: iteration computes tiles 2i (buf0, P1-4) and 2i+1 (buf1, P5-8)
  for (int i = 0; i < 31; ++i) {
    int t = 2 * i;
    PHASE_NB(0, 0, true,  STAGE(1, 0, 0, t + 1), NOSTMT);   // P1
    PHASE_B (0, 1, false, STAGE(1, 0, 1, t + 1), NOSTMT);   // P2
    PHASE_NB(0, 2, false, STAGE(0, 1, 0, t + 2), NOSTMT);   // P3
    PHASE_B (0, 3, false, STAGE(0, 1, 1, t + 2), WAIT_VM4); // P4: tile 2i+1 ready
    PHASE_NB(1, 0, true,  STAGE(0, 0, 0, t + 2), NOSTMT);   // P5
    PHASE_B (1, 1, false, STAGE(0, 0, 1, t + 2), NOSTMT);   // P6
    PHASE_NB(1, 2, false, STAGE(1, 1, 0, t + 3), NOSTMT);   // P7
    PHASE_B (1, 3, false, STAGE(1, 1, 1, t + 3), WAIT_VM4); // P8: tile 2i+2 ready
  }
  // final iteration: tiles 62 (buf0), 63 (buf1); drain
  PHASE_NB(0, 0, true,  STAGE(1, 0, 0, 63), NOSTMT);
  PHASE_B (0, 1, false, STAGE(1, 0, 1, 63), NOSTMT);
  PHASE_NB(0, 2, false, NOSTMT, NOSTMT);
  PHASE_B (0, 3, false, NOSTMT, WAIT_VM0);
  PHASE_NB(1, 0, true,  NOSTMT, NOSTMT);
  PHASE_NB(1, 1, false, NOSTMT, NOSTMT);
  PHASE_NB(1, 2, false, NOSTMT, NOSTMT);
  PHASE_NB(1, 3, false, NOSTMT, NOSTMT);

  // epilogue: C/D layout col=lane&15, row=(lane>>4)*4+reg
  const int r0 = mt * 256 + wm * 128 + fq * 4;
  const int c0 = nt * 256 + wn * 64 + fr;
  #pragma unroll
  for (int nj = 0; nj < 4; ++nj) {
    int col = c0 + nj * 16;
    float bv = bias[col];
    #pragma unroll
    for (int mi = 0; mi < 8; ++mi) {
      size_t base = (size_t)(r0 + mi * 16) * N_DIM + col;
      #pragma unroll
      for (int r = 0; r < 4; ++r)
        out[base + (size_t)r * N_DIM] = acc[mi][nj][r] + bv;
    }
  }
}

// ---------------- fallback (ws too small): naive fp32 ----------------
__global__ void k_fallback(const float* __restrict__ x, const int* __restrict__ qw,
                           const int* __restrict__ qz, const float* __restrict__ sc,
                           const float* __restrict__ bias, float* __restrict__ out) {
  int n = blockIdx.x * blockDim.x + threadIdx.x;
  int m = blockIdx.y;
  const float* xr = x + (size_t)m * K_DIM;
  float acc = 0.f;
  for (int g = 0; g < 32; ++g) {
    float s = sc[g * N_DIM + n];
    int zq = (qz[g * (N_DIM / 8) + (n >> 3)] >> ((n & 7) * 4)) & 15;
    float zs = s * (float)zq;
    for (int k8 = g * 16; k8 < g * 16 + 16; ++k8) {
      int w = qw[(size_t)k8 * N_DIM + n];
      #pragma unroll
      for (int j = 0; j < 8; ++j) {
        float wf = s * (float)((w >> (4 * j)) & 15) - zs;
        acc += wf * xr[k8 * 8 + j];
      }
    }
  }
  out[(size_t)m * N_DIM + n] = acc + bias[n];
}

extern "C" void kernel_launch(void* const* d_in, const int* in_sizes, int n_in,
                              void* d_out, int out_size, void* d_ws, size_t ws_size,
                              hipStream_t stream) {
  const float* x  = (const float*)d_in[0];
  const int* qw   = (const int*)d_in[1];
  const int* qz   = (const int*)d_in[2];
  const float* sc = (const float*)d_in[3];
  const float* bias = (const float*)d_in[4];
  float* out = (float*)d_out;

  const size_t xb_bytes = (size_t)M_DIM * K_DIM * 2;
  const size_t wt_bytes = (size_t)N_DIM * K_DIM * 2;
  const size_t need = xb_bytes + wt_bytes;

  if (ws_size >= need) {
    unsigned short* xb = (unsigned short*)d_ws;
    unsigned short* wt = (unsigned short*)((char*)d_ws + xb_bytes);
    k_convert_x<<<dim3(4096), dim3(256), 0, stream>>>(x, xb);
    k_dequant_w<<<dim3(N_DIM / 256, 64), dim3(256), 0, stream>>>(qw, qz, sc, wt);
    k_gemm<<<dim3((M_DIM / 256) * (N_DIM / 256)), dim3(512), 0, stream>>>(xb, wt, bias, out);
  } else {
    k_fallback<<<dim3(N_DIM / 256, M_DIM), dim3(256), 0, stream>>>(x, qw, qz, sc, bias, out);
  }
}